// Round 1
// baseline (1097.366 us; speedup 1.0000x reference)
//
#include <hip/hip_runtime.h>

#define QN 16384
#define SN 16384
#define FD 64
#define HN 32
#define EN 393216
#define KPAD 68   // 64 + 4 pad, keeps float4 alignment, breaks worst bank conflicts

// ---------------- per-question tables ----------------
// xKpos/xKneg = x@W_K + b_K + h1_bias[ch]; xV = x@W_V + b_V; xQ1 = x@W_Q[0:64]
// xq2[q][g] = sum_f W_K2[g][f] * x[q][f]   (= x @ W_K2^T)
// c2{pos,neg}[q] = scale * sum_f x[q][f]*(b_K2[f] + h2_bias[ch][f])
__global__ __launch_bounds__(256) void p1_kernel(
    const float* __restrict__ x,
    const float* __restrict__ W_K, const float* __restrict__ b_K,
    const float* __restrict__ W_V, const float* __restrict__ b_V,
    const float* __restrict__ W_Q,
    const float* __restrict__ W_K2, const float* __restrict__ b_K2,
    const float* __restrict__ h1b, const float* __restrict__ h2b,
    float* __restrict__ xKpos, float* __restrict__ xKneg,
    float* __restrict__ xV, float* __restrict__ xQ1, float* __restrict__ xq2,
    float* __restrict__ c2pos, float* __restrict__ c2neg)
{
  __shared__ float xs[4 * 64];
  __shared__ float wk2[64 * 65];
  int t = threadIdx.x;
  int r = t >> 6, f = t & 63;
  int q = blockIdx.x * 4 + r;
  xs[r * 64 + f] = x[q * 64 + f];
  for (int i = 0; i < 16; i++) {
    int idx = i * 256 + t;
    wk2[(idx >> 6) * 65 + (idx & 63)] = W_K2[idx];
  }
  __syncthreads();

  float accK = b_K[f], accV = b_V[f], accQ = 0.f;
  for (int g = 0; g < 64; g++) {
    float xv = xs[r * 64 + g];
    accK += xv * W_K[g * 64 + f];
    accV += xv * W_V[g * 64 + f];
    accQ += xv * W_Q[g * 64 + f];
  }
  xKpos[q * 64 + f] = accK + h1b[f];
  xKneg[q * 64 + f] = accK + h1b[64 + f];
  xV[q * 64 + f] = accV;
  xQ1[q * 64 + f] = accQ;

  float acc2 = 0.f;
  for (int g = 0; g < 64; g++) acc2 += wk2[f * 65 + g] * xs[r * 64 + g];
  xq2[q * 64 + f] = acc2;

  float p0 = xs[r * 64 + f] * (b_K2[f] + h2b[f]);
  float p1 = xs[r * 64 + f] * (b_K2[f] + h2b[64 + f]);
  for (int k = 32; k >= 1; k >>= 1) {
    p0 += __shfl_xor(p0, k);
    p1 += __shfl_xor(p1, k);
  }
  if (f == 0) { c2pos[q] = p0 * 0.125f; c2neg[q] = p1 * 0.125f; }
}

// ---------------- per-student tables ----------------
// sQ = s_emb@W_Q[64:128] + b_Q ; sf = s_emb@W_fuse[0:64] + b_fuse
__global__ __launch_bounds__(256) void p2_kernel(
    const float* __restrict__ s_emb,
    const float* __restrict__ W_Q, const float* __restrict__ b_Q,
    const float* __restrict__ W_fuse, const float* __restrict__ b_fuse,
    float* __restrict__ sQ, float* __restrict__ sf)
{
  __shared__ float xs[4 * 64];
  int t = threadIdx.x;
  int r = t >> 6, f = t & 63;
  int s = blockIdx.x * 4 + r;
  xs[r * 64 + f] = s_emb[s * 64 + f];
  __syncthreads();
  float aq = b_Q[f], af = b_fuse[f];
  for (int g = 0; g < 64; g++) {
    float v = xs[r * 64 + g];
    aq += v * W_Q[(64 + g) * 64 + f];
    af += v * W_fuse[g * 64 + f];
  }
  sQ[s * 64 + f] = aq;
  sf[s * 64 + f] = af;
}

// ---------------- CSR build ----------------
__global__ __launch_bounds__(256) void hist_kernel(const int* __restrict__ sid,
                                                   int* __restrict__ cnt, int n) {
  int i = blockIdx.x * 256 + threadIdx.x;
  if (i < n) atomicAdd(&cnt[sid[i]], 1);
}

__global__ __launch_bounds__(256) void scan_kernel(const int* __restrict__ cnt,
                                                   int* __restrict__ offs,
                                                   int* __restrict__ cursor) {
  __shared__ int part[256];
  int t = threadIdx.x;
  int base = t * 64;
  int s = 0;
  for (int i = 0; i < 64; i++) s += cnt[base + i];
  part[t] = s;
  __syncthreads();
  for (int off = 1; off < 256; off <<= 1) {
    int v = (t >= off) ? part[t - off] : 0;
    __syncthreads();
    part[t] += v;
    __syncthreads();
  }
  int run = (t == 0) ? 0 : part[t - 1];
  for (int i = 0; i < 64; i++) {
    int c = cnt[base + i];
    offs[base + i] = run;
    cursor[base + i] = run;
    run += c;
  }
  if (t == 255) offs[SN] = run;
}

__global__ __launch_bounds__(256) void scatter_kernel(
    const int* __restrict__ sid, const int* __restrict__ qid,
    int* __restrict__ cursor, int* __restrict__ csr_qid, int n) {
  int i = blockIdx.x * 256 + threadIdx.x;
  if (i < n) {
    int p = atomicAdd(&cursor[sid[i]], 1);
    csr_qid[p] = qid[i];
  }
}

// ---------------- main per-student kernel ----------------
// Block = one student. Stages hist K/V in LDS, then per batch of 8 edges:
// scores (e,h), masked softmax over h, agg = a@V, s_repr = sf + agg@Wf2,
// sc2 = scale*(s_repr . xq2[qid]) + c2[qid], atomically accumulate
// num[qid] += exp(sc2)*s_repr, den[qid] += exp(sc2).
__global__ __launch_bounds__(256) void main_kernel(
    const float* __restrict__ xKtab, const float* __restrict__ xVtab,
    const float* __restrict__ xQ1, const float* __restrict__ xq2tab,
    const float* __restrict__ c2tab,
    const float* __restrict__ sQ, const float* __restrict__ sf,
    const float* __restrict__ W_fuse,
    const int* __restrict__ hist_qid, const int* __restrict__ hist_cnt,
    const int* __restrict__ offs, const int* __restrict__ csr_qid,
    float* __restrict__ num, float* __restrict__ den)
{
  const int s = blockIdx.x;
  const int t = threadIdx.x;
  __shared__ float Kl[HN * KPAD];
  __shared__ float Vl[HN * KPAD];
  __shared__ float Wf2l[64 * 64];
  __shared__ float sQl[64], sfl[64];
  __shared__ int hql[HN];
  __shared__ float Ql[8 * KPAD];
  __shared__ float X2l[8 * KPAD];
  __shared__ float Al[8 * 33];

  const int cnt = hist_cnt[s];
  if (t < HN) hql[t] = hist_qid[s * HN + t];
  if (t < 64) { sQl[t] = sQ[s * 64 + t]; sfl[t] = sf[s * 64 + t]; }
  for (int i = 0; i < 16; i++) {
    int idx = i * 256 + t;
    Wf2l[idx] = W_fuse[(64 + (idx >> 6)) * 64 + (idx & 63)];
  }
  __syncthreads();
  for (int i = 0; i < 8; i++) {
    int idx = i * 256 + t;
    int h = idx >> 6, f = idx & 63;
    int row = hql[h];
    Kl[h * KPAD + f] = xKtab[row * 64 + f];
    Vl[h * KPAD + f] = xVtab[row * 64 + f];
  }
  const int ebeg = offs[s];
  const int ne = offs[s + 1] - ebeg;
  __syncthreads();

  const float scale = 0.125f;
  const int e = t >> 5;       // 0..7
  const int c = t & 31;       // h for phase S, half-column for phase G

  for (int b0 = 0; b0 < ne; b0 += 8) {
    int nb = min(8, ne - b0);
    // stage per-edge query rows and xq2 rows
    for (int i = 0; i < 2; i++) {
      int idx = i * 256 + t;
      int ee = idx >> 6, f = idx & 63;
      if (ee < nb) {
        int qid = csr_qid[ebeg + b0 + ee];
        Ql[ee * KPAD + f] = xQ1[qid * 64 + f] + sQl[f];
        X2l[ee * KPAD + f] = xq2tab[qid * 64 + f];
      }
    }
    __syncthreads();

    // phase S: scores + masked softmax over h (c == h here)
    float a = 0.f;
    if (e < nb) {
      float sc = 0.f;
      const float4* qp = (const float4*)&Ql[e * KPAD];
      const float4* kp = (const float4*)&Kl[c * KPAD];
      for (int i = 0; i < 16; i++) {
        float4 qv = qp[i];
        float4 kv = kp[i];
        sc += qv.x * kv.x + qv.y * kv.y + qv.z * kv.z + qv.w * kv.w;
      }
      sc *= scale;
      float m = (c < cnt) ? sc : -1e30f;
      for (int k = 16; k >= 1; k >>= 1) m = fmaxf(m, __shfl_xor(m, k, 32));
      float ew = (c < cnt) ? __expf(sc - m) : 0.f;
      float d = ew;
      for (int k = 16; k >= 1; k >>= 1) d += __shfl_xor(d, k, 32);
      a = (d > 0.f) ? ew / d : 0.f;
    }
    Al[e * 33 + c] = a;
    __syncthreads();

    // phase G part 1: agg = a @ V   (thread owns (e, f=c) and (e, f=c+32))
    if (e < nb) {
      float ag0 = 0.f, ag1 = 0.f;
      for (int hh = 0; hh < HN; hh++) {
        float av = Al[e * 33 + hh];
        ag0 += av * Vl[hh * KPAD + c];
        ag1 += av * Vl[hh * KPAD + c + 32];
      }
      Ql[e * KPAD + c] = ag0;          // reuse Ql as agg scratch
      Ql[e * KPAD + c + 32] = ag1;
    }
    __syncthreads();

    // phase G part 2: fuse GEMV, sc2 dot, exp, atomics
    if (e < nb) {
      int qid = csr_qid[ebeg + b0 + e];
      float r0 = sfl[c], r1 = sfl[c + 32];
      for (int g = 0; g < 64; g++) {
        float ag = Ql[e * KPAD + g];
        r0 += ag * Wf2l[g * 64 + c];
        r1 += ag * Wf2l[g * 64 + c + 32];
      }
      float p = r0 * X2l[e * KPAD + c] + r1 * X2l[e * KPAD + c + 32];
      for (int k = 16; k >= 1; k >>= 1) p += __shfl_xor(p, k, 32);
      float sc2 = p * scale + c2tab[qid];
      float ew = __expf(sc2);
      if (c == 0) atomicAdd(&den[qid], ew);
      atomicAdd(&num[qid * 64 + c], ew * r0);
      atomicAdd(&num[qid * 64 + c + 32], ew * r1);
    }
    __syncthreads();
  }
}

// ---------------- final projection ----------------
// r_ch = num/den (0 if den==0); h_ch = r_ch@W_V2 + b_V2 (0 if den==0);
// out = h_pos@W_proj[0:64] + h_neg@W_proj[64:128] + b_proj
__global__ __launch_bounds__(256) void final_kernel(
    const float* __restrict__ num_pos, const float* __restrict__ den_pos,
    const float* __restrict__ num_neg, const float* __restrict__ den_neg,
    const float* __restrict__ W_V2, const float* __restrict__ b_V2,
    const float* __restrict__ W_proj, const float* __restrict__ b_proj,
    float* __restrict__ out)
{
  __shared__ float hp[4][64], hn[4][64];
  int t = threadIdx.x;
  int r = t >> 6, j = t & 63;
  int q = blockIdx.x * 4 + r;

  float dp = den_pos[q];
  float acc = 0.f;
  if (dp > 0.f) {
    acc = b_V2[j];
    float inv = 1.f / dp;
    for (int f = 0; f < 64; f++) acc += (num_pos[q * 64 + f] * inv) * W_V2[f * 64 + j];
  }
  hp[r][j] = acc;

  float dn = den_neg[q];
  acc = 0.f;
  if (dn > 0.f) {
    acc = b_V2[j];
    float inv = 1.f / dn;
    for (int f = 0; f < 64; f++) acc += (num_neg[q * 64 + f] * inv) * W_V2[f * 64 + j];
  }
  hn[r][j] = acc;
  __syncthreads();

  float o = b_proj[j];
  for (int f = 0; f < 64; f++) {
    o += hp[r][f] * W_proj[f * 64 + j];
    o += hn[r][f] * W_proj[(64 + f) * 64 + j];
  }
  out[q * 64 + j] = o;
}

extern "C" void kernel_launch(void* const* d_in, const int* in_sizes, int n_in,
                              void* d_out, int out_size, void* d_ws, size_t ws_size,
                              hipStream_t stream) {
  const float* x      = (const float*)d_in[0];
  const float* s_emb  = (const float*)d_in[1];
  const float* W_Q    = (const float*)d_in[2];
  const float* b_Q    = (const float*)d_in[3];
  const float* W_K    = (const float*)d_in[4];
  const float* b_K    = (const float*)d_in[5];
  const float* W_V    = (const float*)d_in[6];
  const float* b_V    = (const float*)d_in[7];
  const float* W_fuse = (const float*)d_in[8];
  const float* b_fuse = (const float*)d_in[9];
  const float* W_K2   = (const float*)d_in[10];
  const float* b_K2   = (const float*)d_in[11];
  const float* W_V2   = (const float*)d_in[12];
  const float* b_V2   = (const float*)d_in[13];
  const float* W_proj = (const float*)d_in[14];
  const float* b_proj = (const float*)d_in[15];
  const float* h1b    = (const float*)d_in[16];
  const float* h2b    = (const float*)d_in[17];
  const int* hq_pos   = (const int*)d_in[18];
  const int* hc_pos   = (const int*)d_in[19];
  const int* hq_neg   = (const int*)d_in[20];
  const int* hc_neg   = (const int*)d_in[21];
  const int* es_pos   = (const int*)d_in[22];
  const int* eq_pos   = (const int*)d_in[23];
  const int* es_neg   = (const int*)d_in[24];
  const int* eq_neg   = (const int*)d_in[25];
  float* out = (float*)d_out;

  // ---- workspace carve (bump allocator, 256B aligned) ----
  size_t off = 0;
  char* base = (char*)d_ws;
  auto carve = [&](size_t bytes) -> void* {
    void* p = base + off;
    off += (bytes + 255) & ~(size_t)255;
    return p;
  };
  // zero-init region first (single memset)
  float* num_pos = (float*)carve((size_t)QN * 64 * 4);
  float* num_neg = (float*)carve((size_t)QN * 64 * 4);
  float* den_pos = (float*)carve((size_t)QN * 4);
  float* den_neg = (float*)carve((size_t)QN * 4);
  int* cnt_pos   = (int*)carve((size_t)SN * 4);
  int* cnt_neg   = (int*)carve((size_t)SN * 4);
  size_t zero_bytes = off;
  // non-zeroed
  float* xKpos = (float*)carve((size_t)QN * 64 * 4);
  float* xKneg = (float*)carve((size_t)QN * 64 * 4);
  float* xV    = (float*)carve((size_t)QN * 64 * 4);
  float* xQ1   = (float*)carve((size_t)QN * 64 * 4);
  float* xq2   = (float*)carve((size_t)QN * 64 * 4);
  float* sQ    = (float*)carve((size_t)SN * 64 * 4);
  float* sf    = (float*)carve((size_t)SN * 64 * 4);
  float* c2pos = (float*)carve((size_t)QN * 4);
  float* c2neg = (float*)carve((size_t)QN * 4);
  int* offs_pos = (int*)carve((size_t)(SN + 1) * 4);
  int* offs_neg = (int*)carve((size_t)(SN + 1) * 4);
  int* cur_pos  = (int*)carve((size_t)SN * 4);
  int* cur_neg  = (int*)carve((size_t)SN * 4);
  int* csr_pos  = (int*)carve((size_t)EN * 4);
  int* csr_neg  = (int*)carve((size_t)EN * 4);
  if (off > ws_size) return;  // workspace too small: fail loudly via wrong output

  hipMemsetAsync(d_ws, 0, zero_bytes, stream);

  p1_kernel<<<QN / 4, 256, 0, stream>>>(x, W_K, b_K, W_V, b_V, W_Q, W_K2, b_K2,
                                        h1b, h2b, xKpos, xKneg, xV, xQ1, xq2,
                                        c2pos, c2neg);
  p2_kernel<<<SN / 4, 256, 0, stream>>>(s_emb, W_Q, b_Q, W_fuse, b_fuse, sQ, sf);

  hist_kernel<<<EN / 256, 256, 0, stream>>>(es_pos, cnt_pos, EN);
  hist_kernel<<<EN / 256, 256, 0, stream>>>(es_neg, cnt_neg, EN);
  scan_kernel<<<1, 256, 0, stream>>>(cnt_pos, offs_pos, cur_pos);
  scan_kernel<<<1, 256, 0, stream>>>(cnt_neg, offs_neg, cur_neg);
  scatter_kernel<<<EN / 256, 256, 0, stream>>>(es_pos, eq_pos, cur_pos, csr_pos, EN);
  scatter_kernel<<<EN / 256, 256, 0, stream>>>(es_neg, eq_neg, cur_neg, csr_neg, EN);

  main_kernel<<<SN, 256, 0, stream>>>(xKpos, xV, xQ1, xq2, c2pos, sQ, sf, W_fuse,
                                      hq_pos, hc_pos, offs_pos, csr_pos,
                                      num_pos, den_pos);
  main_kernel<<<SN, 256, 0, stream>>>(xKneg, xV, xQ1, xq2, c2neg, sQ, sf, W_fuse,
                                      hq_neg, hc_neg, offs_neg, csr_neg,
                                      num_neg, den_neg);

  final_kernel<<<QN / 4, 256, 0, stream>>>(num_pos, den_pos, num_neg, den_neg,
                                           W_V2, b_V2, W_proj, b_proj, out);
}

// Round 2
// 638.685 us; speedup vs baseline: 1.7182x; 1.7182x over previous
//
#include <hip/hip_runtime.h>

#define QN 16384
#define SN 16384
#define FD 64
#define HN 32
#define EN 393216
#define KPAD 68   // 64 + 4 pad for K tile (float4-aligned, measured 0 conflicts)

// ---------------- per-question tables ----------------
// xKpos/xKneg = x@W_K + b_K + h1_bias[ch]
// xVf  = (x@W_V + b_V) @ W_fuse[64:128]   (fuse GEMV folded per-question)
// xQ1  = x@W_Q[0:64]
// xq2[q][a] = sum_b W_K2[a][b] * x[q][b]  (= x @ W_K2^T)
// c2{pos,neg}[q] = scale * sum_f x[q][f]*(b_K2[f] + h2_bias[ch][f])
__global__ __launch_bounds__(256) void p1_kernel(
    const float* __restrict__ x,
    const float* __restrict__ W_K, const float* __restrict__ b_K,
    const float* __restrict__ W_V, const float* __restrict__ b_V,
    const float* __restrict__ W_Q,
    const float* __restrict__ W_K2, const float* __restrict__ b_K2,
    const float* __restrict__ W_fuse,
    const float* __restrict__ h1b, const float* __restrict__ h2b,
    float* __restrict__ xKpos, float* __restrict__ xKneg,
    float* __restrict__ xVf, float* __restrict__ xQ1, float* __restrict__ xq2,
    float* __restrict__ c2pos, float* __restrict__ c2neg)
{
  __shared__ float xs[4 * 64];
  __shared__ float vs[4 * 64];
  __shared__ float wk2[64 * 65];
  int t = threadIdx.x;
  int r = t >> 6, f = t & 63;
  int q = blockIdx.x * 4 + r;
  xs[r * 64 + f] = x[q * 64 + f];
  for (int i = 0; i < 16; i++) {
    int idx = i * 256 + t;
    wk2[(idx >> 6) * 65 + (idx & 63)] = W_K2[idx];
  }
  __syncthreads();

  float accK = b_K[f], accV = b_V[f], accQ = 0.f;
  for (int g = 0; g < 64; g++) {
    float xv = xs[r * 64 + g];
    accK += xv * W_K[g * 64 + f];
    accV += xv * W_V[g * 64 + f];
    accQ += xv * W_Q[g * 64 + f];
  }
  xKpos[q * 64 + f] = accK + h1b[f];
  xKneg[q * 64 + f] = accK + h1b[64 + f];
  xQ1[q * 64 + f] = accQ;
  vs[r * 64 + f] = accV;

  float acc2 = 0.f;
  for (int g = 0; g < 64; g++) acc2 += wk2[f * 65 + g] * xs[r * 64 + g];
  xq2[q * 64 + f] = acc2;

  float p0 = xs[r * 64 + f] * (b_K2[f] + h2b[f]);
  float p1 = xs[r * 64 + f] * (b_K2[f] + h2b[64 + f]);
  for (int k = 32; k >= 1; k >>= 1) {
    p0 += __shfl_xor(p0, k);
    p1 += __shfl_xor(p1, k);
  }
  if (f == 0) { c2pos[q] = p0 * 0.125f; c2neg[q] = p1 * 0.125f; }

  __syncthreads();
  float accVf = 0.f;
  for (int g = 0; g < 64; g++) accVf += vs[r * 64 + g] * W_fuse[(64 + g) * 64 + f];
  xVf[q * 64 + f] = accVf;
}

// ---------------- per-student tables ----------------
// sQ = s_emb@W_Q[64:128] + b_Q ; sf = s_emb@W_fuse[0:64] + b_fuse
__global__ __launch_bounds__(256) void p2_kernel(
    const float* __restrict__ s_emb,
    const float* __restrict__ W_Q, const float* __restrict__ b_Q,
    const float* __restrict__ W_fuse, const float* __restrict__ b_fuse,
    float* __restrict__ sQ, float* __restrict__ sf)
{
  __shared__ float xs[4 * 64];
  int t = threadIdx.x;
  int r = t >> 6, f = t & 63;
  int s = blockIdx.x * 4 + r;
  xs[r * 64 + f] = s_emb[s * 64 + f];
  __syncthreads();
  float aq = b_Q[f], af = b_fuse[f];
  for (int g = 0; g < 64; g++) {
    float v = xs[r * 64 + g];
    aq += v * W_Q[(64 + g) * 64 + f];
    af += v * W_fuse[g * 64 + f];
  }
  sQ[s * 64 + f] = aq;
  sf[s * 64 + f] = af;
}

// ---------------- CSR build (both channels via blockIdx.y) ----------------
__global__ __launch_bounds__(256) void hist_kernel(
    const int* __restrict__ sid_pos, const int* __restrict__ sid_neg,
    int* __restrict__ cnt_pos, int* __restrict__ cnt_neg, int n) {
  const int* sid = blockIdx.y ? sid_neg : sid_pos;
  int* cnt = blockIdx.y ? cnt_neg : cnt_pos;
  int i = blockIdx.x * 256 + threadIdx.x;
  if (i < n) atomicAdd(&cnt[sid[i]], 1);
}

__global__ __launch_bounds__(256) void scan_kernel(
    const int* __restrict__ cnt_pos, int* __restrict__ offs_pos, int* __restrict__ cur_pos,
    const int* __restrict__ cnt_neg, int* __restrict__ offs_neg, int* __restrict__ cur_neg) {
  const int* cnt = blockIdx.y ? cnt_neg : cnt_pos;
  int* offs = blockIdx.y ? offs_neg : offs_pos;
  int* cursor = blockIdx.y ? cur_neg : cur_pos;
  __shared__ int part[256];
  int t = threadIdx.x;
  int base = t * 64;
  int s = 0;
  for (int i = 0; i < 64; i++) s += cnt[base + i];
  part[t] = s;
  __syncthreads();
  for (int off = 1; off < 256; off <<= 1) {
    int v = (t >= off) ? part[t - off] : 0;
    __syncthreads();
    part[t] += v;
    __syncthreads();
  }
  int run = (t == 0) ? 0 : part[t - 1];
  for (int i = 0; i < 64; i++) {
    int c = cnt[base + i];
    offs[base + i] = run;
    cursor[base + i] = run;
    run += c;
  }
  if (t == 255) offs[SN] = run;
}

__global__ __launch_bounds__(256) void scatter_kernel(
    const int* __restrict__ sid_pos, const int* __restrict__ qid_pos,
    int* __restrict__ cur_pos, int* __restrict__ csr_pos,
    const int* __restrict__ sid_neg, const int* __restrict__ qid_neg,
    int* __restrict__ cur_neg, int* __restrict__ csr_neg, int n) {
  const int* sid = blockIdx.y ? sid_neg : sid_pos;
  const int* qid = blockIdx.y ? qid_neg : qid_pos;
  int* cursor = blockIdx.y ? cur_neg : cur_pos;
  int* csr_qid = blockIdx.y ? csr_neg : csr_pos;
  int i = blockIdx.x * 256 + threadIdx.x;
  if (i < n) {
    int p = atomicAdd(&cursor[sid[i]], 1);
    csr_qid[p] = qid[i];
  }
}

// ---------------- main per-student kernel (both channels) ----------------
// Block = (student, channel). Stage hist K/Vf rows in LDS once; per batch of
// 8 edges: stage q-rows, then each 32-lane group does: score -> in-wave
// softmax -> agg over Vf (s_repr = sf + a@Vf_rows) -> sc2 dot vs xq2[qid]
// -> exp -> atomics into num/den. Only 2 barriers per batch.
__global__ __launch_bounds__(256) void main_kernel(
    const float* __restrict__ xKpos, const float* __restrict__ xKneg,
    const float* __restrict__ xVf, const float* __restrict__ xQ1,
    const float* __restrict__ xq2tab,
    const float* __restrict__ c2pos, const float* __restrict__ c2neg,
    const float* __restrict__ sQ, const float* __restrict__ sf,
    const int* __restrict__ hq_pos, const int* __restrict__ hc_pos,
    const int* __restrict__ hq_neg, const int* __restrict__ hc_neg,
    const int* __restrict__ offs_pos, const int* __restrict__ csr_pos,
    const int* __restrict__ offs_neg, const int* __restrict__ csr_neg,
    float* __restrict__ num_pos, float* __restrict__ den_pos,
    float* __restrict__ num_neg, float* __restrict__ den_neg)
{
  const int s = blockIdx.x;
  const int ch = blockIdx.y;
  const float* __restrict__ xK = ch ? xKneg : xKpos;
  const float* __restrict__ c2 = ch ? c2neg : c2pos;
  const int* __restrict__ hq = ch ? hq_neg : hq_pos;
  const int* __restrict__ hc = ch ? hc_neg : hc_pos;
  const int* __restrict__ offs = ch ? offs_neg : offs_pos;
  const int* __restrict__ csr = ch ? csr_neg : csr_pos;
  float* __restrict__ num = ch ? num_neg : num_pos;
  float* __restrict__ den = ch ? den_neg : den_pos;

  const int t = threadIdx.x;
  __shared__ float Kl[HN * KPAD];   // 8704 B
  __shared__ float Vl[HN * 64];     // 8192 B (scalar-read, conflict-free)
  __shared__ float Ql[8 * 64];      // 2048 B
  __shared__ float Al[8 * 33];      // 1056 B
  __shared__ float sQl[64], sfl[64];
  __shared__ int hql[HN];
  __shared__ int qidl[8];

  const int cnt = hc[s];
  if (t < HN) hql[t] = hq[s * HN + t];
  if (t >= 64 && t < 192) {
    int j = t - 64;
    if (j < 64) sQl[j] = sQ[s * 64 + j];
    else sfl[j - 64] = sf[s * 64 + (j - 64)];
  }
  __syncthreads();
  // gather history rows as float4 (512 float4 per table, 2 per thread)
  for (int i = 0; i < 2; i++) {
    int idx = i * 256 + t;
    int h = idx >> 4, j = idx & 15;
    int row = hql[h];
    *(float4*)&Kl[h * KPAD + j * 4] = *(const float4*)&xK[row * 64 + j * 4];
    *(float4*)&Vl[h * 64 + j * 4] = *(const float4*)&xVf[row * 64 + j * 4];
  }
  const int ebeg = offs[s];
  const int ne = offs[s + 1] - ebeg;
  // NOTE: no barrier here — the staging barrier inside the loop covers the
  // gather writes before any compute reads Kl/Vl.

  const float scale = 0.125f;
  const int e = t >> 5;       // 0..7  edge within batch
  const int c = t & 31;       // lane within edge group

  for (int b0 = 0; b0 < ne; b0 += 8) {
    int nb = min(8, ne - b0);
    // stage q-rows (float4): 8 edges x 16 float4 = 128 threads
    if (t < 128) {
      int ee = t >> 4, j = t & 15;
      if (ee < nb) {
        int qq = csr[ebeg + b0 + ee];
        if (j == 0) qidl[ee] = qq;
        float4 qv = *(const float4*)&xQ1[qq * 64 + j * 4];
        float4 sv = *(const float4*)&sQl[j * 4];
        qv.x += sv.x; qv.y += sv.y; qv.z += sv.z; qv.w += sv.w;
        *(float4*)&Ql[ee * 64 + j * 4] = qv;
      }
    }
    __syncthreads();

    if (e < nb) {
      // score: lane c = history slot h
      float sc = 0.f;
      const float4* qp = (const float4*)&Ql[e * 64];
      const float4* kp = (const float4*)&Kl[c * KPAD];
      for (int i = 0; i < 16; i++) {
        float4 qv = qp[i];
        float4 kv = kp[i];
        sc += qv.x * kv.x + qv.y * kv.y + qv.z * kv.z + qv.w * kv.w;
      }
      sc *= scale;
      float m = (c < cnt) ? sc : -1e30f;
      for (int k = 16; k >= 1; k >>= 1) m = fmaxf(m, __shfl_xor(m, k, 32));
      float ew = (c < cnt) ? __expf(sc - m) : 0.f;
      float d = ew;
      for (int k = 16; k >= 1; k >>= 1) d += __shfl_xor(d, k, 32);
      float a = (d > 0.f) ? ew / d : 0.f;
      // same-wave write/read: no __syncthreads needed (compiler emits lgkmcnt)
      Al[e * 33 + c] = a;

      // agg directly in fused space: r = sf + a @ Vf_rows ; lane owns f=c,c+32
      float r0 = sfl[c], r1 = sfl[c + 32];
      for (int hh = 0; hh < HN; hh++) {
        float av = Al[e * 33 + hh];
        r0 += av * Vl[hh * 64 + c];
        r1 += av * Vl[hh * 64 + c + 32];
      }
      int qq = qidl[e];
      float p = r0 * xq2tab[qq * 64 + c] + r1 * xq2tab[qq * 64 + c + 32];
      for (int k = 16; k >= 1; k >>= 1) p += __shfl_xor(p, k, 32);
      float sc2 = p * scale + c2[qq];
      float ew2 = __expf(sc2);
      atomicAdd(&num[qq * 64 + c], ew2 * r0);
      atomicAdd(&num[qq * 64 + c + 32], ew2 * r1);
      if (c == 0) atomicAdd(&den[qq], ew2);
    }
    __syncthreads();
  }
}

// ---------------- final projection ----------------
__global__ __launch_bounds__(256) void final_kernel(
    const float* __restrict__ num_pos, const float* __restrict__ den_pos,
    const float* __restrict__ num_neg, const float* __restrict__ den_neg,
    const float* __restrict__ W_V2, const float* __restrict__ b_V2,
    const float* __restrict__ W_proj, const float* __restrict__ b_proj,
    float* __restrict__ out)
{
  __shared__ float hp[4][64], hn[4][64];
  int t = threadIdx.x;
  int r = t >> 6, j = t & 63;
  int q = blockIdx.x * 4 + r;

  float dp = den_pos[q];
  float acc = 0.f;
  if (dp > 0.f) {
    acc = b_V2[j];
    float inv = 1.f / dp;
    for (int f = 0; f < 64; f++) acc += (num_pos[q * 64 + f] * inv) * W_V2[f * 64 + j];
  }
  hp[r][j] = acc;

  float dn = den_neg[q];
  acc = 0.f;
  if (dn > 0.f) {
    acc = b_V2[j];
    float inv = 1.f / dn;
    for (int f = 0; f < 64; f++) acc += (num_neg[q * 64 + f] * inv) * W_V2[f * 64 + j];
  }
  hn[r][j] = acc;
  __syncthreads();

  float o = b_proj[j];
  for (int f = 0; f < 64; f++) {
    o += hp[r][f] * W_proj[f * 64 + j];
    o += hn[r][f] * W_proj[(64 + f) * 64 + j];
  }
  out[q * 64 + j] = o;
}

extern "C" void kernel_launch(void* const* d_in, const int* in_sizes, int n_in,
                              void* d_out, int out_size, void* d_ws, size_t ws_size,
                              hipStream_t stream) {
  const float* x      = (const float*)d_in[0];
  const float* s_emb  = (const float*)d_in[1];
  const float* W_Q    = (const float*)d_in[2];
  const float* b_Q    = (const float*)d_in[3];
  const float* W_K    = (const float*)d_in[4];
  const float* b_K    = (const float*)d_in[5];
  const float* W_V    = (const float*)d_in[6];
  const float* b_V    = (const float*)d_in[7];
  const float* W_fuse = (const float*)d_in[8];
  const float* b_fuse = (const float*)d_in[9];
  const float* W_K2   = (const float*)d_in[10];
  const float* b_K2   = (const float*)d_in[11];
  const float* W_V2   = (const float*)d_in[12];
  const float* b_V2   = (const float*)d_in[13];
  const float* W_proj = (const float*)d_in[14];
  const float* b_proj = (const float*)d_in[15];
  const float* h1b    = (const float*)d_in[16];
  const float* h2b    = (const float*)d_in[17];
  const int* hq_pos   = (const int*)d_in[18];
  const int* hc_pos   = (const int*)d_in[19];
  const int* hq_neg   = (const int*)d_in[20];
  const int* hc_neg   = (const int*)d_in[21];
  const int* es_pos   = (const int*)d_in[22];
  const int* eq_pos   = (const int*)d_in[23];
  const int* es_neg   = (const int*)d_in[24];
  const int* eq_neg   = (const int*)d_in[25];
  float* out = (float*)d_out;

  // ---- workspace carve (bump allocator, 256B aligned) ----
  size_t off = 0;
  char* base = (char*)d_ws;
  auto carve = [&](size_t bytes) -> void* {
    void* p = base + off;
    off += (bytes + 255) & ~(size_t)255;
    return p;
  };
  // zero-init region first (single memset)
  float* num_pos = (float*)carve((size_t)QN * 64 * 4);
  float* num_neg = (float*)carve((size_t)QN * 64 * 4);
  float* den_pos = (float*)carve((size_t)QN * 4);
  float* den_neg = (float*)carve((size_t)QN * 4);
  int* cnt_pos   = (int*)carve((size_t)SN * 4);
  int* cnt_neg   = (int*)carve((size_t)SN * 4);
  size_t zero_bytes = off;
  // non-zeroed
  float* xKpos = (float*)carve((size_t)QN * 64 * 4);
  float* xKneg = (float*)carve((size_t)QN * 64 * 4);
  float* xVf   = (float*)carve((size_t)QN * 64 * 4);
  float* xQ1   = (float*)carve((size_t)QN * 64 * 4);
  float* xq2   = (float*)carve((size_t)QN * 64 * 4);
  float* sQ    = (float*)carve((size_t)SN * 64 * 4);
  float* sf    = (float*)carve((size_t)SN * 64 * 4);
  float* c2pos = (float*)carve((size_t)QN * 4);
  float* c2neg = (float*)carve((size_t)QN * 4);
  int* offs_pos = (int*)carve((size_t)(SN + 1) * 4);
  int* offs_neg = (int*)carve((size_t)(SN + 1) * 4);
  int* cur_pos  = (int*)carve((size_t)SN * 4);
  int* cur_neg  = (int*)carve((size_t)SN * 4);
  int* csr_pos  = (int*)carve((size_t)EN * 4);
  int* csr_neg  = (int*)carve((size_t)EN * 4);
  if (off > ws_size) return;

  hipMemsetAsync(d_ws, 0, zero_bytes, stream);

  p1_kernel<<<QN / 4, 256, 0, stream>>>(x, W_K, b_K, W_V, b_V, W_Q, W_K2, b_K2,
                                        W_fuse, h1b, h2b, xKpos, xKneg, xVf, xQ1,
                                        xq2, c2pos, c2neg);
  p2_kernel<<<SN / 4, 256, 0, stream>>>(s_emb, W_Q, b_Q, W_fuse, b_fuse, sQ, sf);

  hist_kernel<<<dim3(EN / 256, 2), 256, 0, stream>>>(es_pos, es_neg, cnt_pos, cnt_neg, EN);
  scan_kernel<<<dim3(1, 2), 256, 0, stream>>>(cnt_pos, offs_pos, cur_pos,
                                              cnt_neg, offs_neg, cur_neg);
  scatter_kernel<<<dim3(EN / 256, 2), 256, 0, stream>>>(es_pos, eq_pos, cur_pos, csr_pos,
                                                        es_neg, eq_neg, cur_neg, csr_neg, EN);

  main_kernel<<<dim3(SN, 2), 256, 0, stream>>>(
      xKpos, xKneg, xVf, xQ1, xq2, c2pos, c2neg, sQ, sf,
      hq_pos, hc_pos, hq_neg, hc_neg,
      offs_pos, csr_pos, offs_neg, csr_neg,
      num_pos, den_pos, num_neg, den_neg);

  final_kernel<<<QN / 4, 256, 0, stream>>>(num_pos, den_pos, num_neg, den_neg,
                                           W_V2, b_V2, W_proj, b_proj, out);
}